// Round 7
// baseline (10368.049 us; speedup 1.0000x reference)
//
#include <hip/hip_runtime.h>
#include <hip/hip_bf16.h>
#include <cstdint>

#define S_ 512
#define B_ 32
#define E_ 512
#define H_ 256
#define C_ 16

typedef float f32x4_t __attribute__((ext_vector_type(4)));
typedef __bf16 bf16x8_t __attribute__((ext_vector_type(8)));

__device__ __forceinline__ float bf2f(unsigned short u) {
    return __uint_as_float(((unsigned int)u) << 16);
}
__device__ __forceinline__ unsigned short f2bf(float f) {
    unsigned int u = __float_as_uint(f);
    unsigned int r = (u + 0x7FFFu + ((u >> 16) & 1u)) >> 16;
    return (unsigned short)r;
}
__device__ __forceinline__ float sigf(float x) { return 1.f / (1.f + __expf(-x)); }
__device__ __forceinline__ float tanhf_fast(float x) {
    float e = __expf(-2.f * fabsf(x));
    float r = (1.f - e) / (1.f + e);
    return x >= 0.f ? r : -r;
}

// ---------------- embedding gather -> bf16 X[s*32+b][0:512] ----------------
__global__ __launch_bounds__(128) void embed_gather(
    const int* __restrict__ x, const float* __restrict__ emb, unsigned short* __restrict__ X)
{
    int row = blockIdx.x;           // s*32 + b
    int s = row >> 5, b = row & 31;
    int idx = x[b * S_ + s];
    float4 v = ((const float4*)(emb + (size_t)idx * E_))[threadIdx.x];
    ushort4 o; o.x = f2bf(v.x); o.y = f2bf(v.y); o.z = f2bf(v.z); o.w = f2bf(v.w);
    ((ushort4*)(X + (size_t)row * E_))[threadIdx.x] = o;
}

// ---------------- f32 -> bf16 converter (n multiple of 4) ----------------
__global__ __launch_bounds__(256) void conv_f2b(
    const float* __restrict__ src, unsigned short* __restrict__ dst, int n)
{
    int i = (blockIdx.x * 256 + threadIdx.x) * 4;
    if (i < n) {
        float4 v = *(const float4*)(src + i);
        ushort4 o; o.x = f2bf(v.x); o.y = f2bf(v.y); o.z = f2bf(v.z); o.w = f2bf(v.w);
        *(ushort4*)(dst + i) = o;
    }
}

// ---------------- bf16 MFMA GEMM: C[M,N] = A[M,K] @ W[N,K]^T (+b1+b2) ----------------
// 64x64 tile, 256 thr (4 waves), BK=64.
// STORE_MODE: 0 = f32 row-major, 1 = bf16 row-major, 2 = bf16 permuted [m>>5][n][32 b]
template<int STORE_MODE>
__global__ __launch_bounds__(256) void gemm_bf16(
    const unsigned short* __restrict__ A, const unsigned short* __restrict__ W,
    const float* __restrict__ b1, const float* __restrict__ b2,
    void* __restrict__ Cout, int M, int N, int K)
{
    __shared__ __align__(16) char lds[16384];   // A-tile 8K + W-tile 8K, swizzled
    char* asb = lds;
    char* wsb = lds + 8192;
    const int tid = threadIdx.x;
    const int m0 = blockIdx.x * 64, n0 = blockIdx.y * 64;
    const int w = tid >> 6, L = tid & 63;
    const int sr = tid >> 2, sq = tid & 3;
    const int mrow = L & 15, kg = (L >> 4) * 8;
    f32x4_t acc[4];
    #pragma unroll
    for (int ni = 0; ni < 4; ++ni) acc[ni] = f32x4_t{0.f, 0.f, 0.f, 0.f};

    for (int k0 = 0; k0 < K; k0 += 64) {
        uint4 av1 = *(const uint4*)(A + (size_t)(m0 + sr) * K + k0 + sq * 16);
        uint4 av2 = *(const uint4*)(A + (size_t)(m0 + sr) * K + k0 + sq * 16 + 8);
        uint4 wv1 = *(const uint4*)(W + (size_t)(n0 + sr) * K + k0 + sq * 16);
        uint4 wv2 = *(const uint4*)(W + (size_t)(n0 + sr) * K + k0 + sq * 16 + 8);
        __syncthreads();
        int sw = (sr & 7) << 4;
        *(uint4*)(asb + ((sr * 128 + sq * 32) ^ sw))      = av1;
        *(uint4*)(asb + ((sr * 128 + sq * 32 + 16) ^ sw)) = av2;
        *(uint4*)(wsb + ((sr * 128 + sq * 32) ^ sw))      = wv1;
        *(uint4*)(wsb + ((sr * 128 + sq * 32 + 16) ^ sw)) = wv2;
        __syncthreads();
        #pragma unroll
        for (int kb = 0; kb < 2; ++kb) {
            int kl = kb * 32 + kg;
            int ar = w * 16 + mrow;
            bf16x8_t a = *(const bf16x8_t*)(asb + ((ar * 128 + kl * 2) ^ ((ar & 7) << 4)));
            #pragma unroll
            for (int ni = 0; ni < 4; ++ni) {
                int nr = ni * 16 + mrow;
                bf16x8_t b = *(const bf16x8_t*)(wsb + ((nr * 128 + kl * 2) ^ ((nr & 7) << 4)));
                acc[ni] = __builtin_amdgcn_mfma_f32_16x16x32_bf16(a, b, acc[ni], 0, 0, 0);
            }
        }
    }
    #pragma unroll
    for (int ni = 0; ni < 4; ++ni) {
        int n = n0 + ni * 16 + mrow;
        float bb = (b1 ? b1[n] : 0.f) + (b2 ? b2[n] : 0.f);
        #pragma unroll
        for (int r = 0; r < 4; ++r) {
            int m = m0 + w * 16 + (L >> 4) * 4 + r;
            float v = acc[ni][r] + bb;
            if (STORE_MODE == 2) {
                int tq = m >> 5, b = m & 31;
                ((unsigned short*)Cout)[((size_t)tq * N + n) * 32 + b] = f2bf(v);
            } else if (STORE_MODE == 1) {
                ((unsigned short*)Cout)[(size_t)m * N + n] = f2bf(v);
            } else {
                ((float*)Cout)[(size_t)m * N + n] = v;
            }
        }
    }
}

// ---------------- LSTM recurrence v4: 4 blocks = 2 dir x 2 batch-halves ----------------
// NO cross-block communication (batches are independent recurrences).
// Block: 256 thr (4 waves, 1/SIMD -> 512 unified VGPR budget). Wave w owns units
// [w*64, w*64+64) x 4 gates = 256 rows. Weights: kt{0,1} all rows in LDS (128KB),
// (kt==2, jt==0) in LDS (16KB compact), rest in registers (92 frags = 368 VGPR/lane).
// h [16 b][256 u] bf16 swizzled in LDS (8KB). Zx pre-permuted to [t][n][32 b].
__global__ __launch_bounds__(256, 1) void lstm_rec4(
    const unsigned short* __restrict__ Zf,   // [512][1024][32] bf16 permuted
    const unsigned short* __restrict__ Zb,
    const unsigned short* __restrict__ whhb, // [2][1024][256] bf16 (this layer)
    unsigned short* __restrict__ Hb)         // [512*32][512] bf16
{
    __shared__ __align__(16) char lds[155648];  // A:0..128K, B:128K..144K, h:144K..152K
    const int tid = threadIdx.x;
    const int d  = blockIdx.x >> 1;
    const int bh = blockIdx.x & 1;
    const int w = tid >> 6, L = tid & 63;
    const int lr = L & 15;
    const int kq = L >> 4;
    const int kg8 = kq * 8;
    const unsigned short* Z = d ? Zb : Zf;
    const unsigned short* Wd = whhb + (size_t)d * 262144;
    const int hbase = 147456;

    // ---- stage LDS region A: all 1024 rows, k in [0,64) ----
    for (int i = 0; i < 32; ++i) {
        int c = i * 256 + tid;
        int row = c >> 3, seg = c & 7;
        uint4 v = *(const uint4*)(Wd + (size_t)row * 256 + seg * 8);
        *(uint4*)(lds + ((row * 128 + seg * 16) ^ ((row & 7) << 4))) = v;
    }
    // ---- stage LDS region B: (kt==2, jt==0): 256 compact rows, k in [64,96) ----
    // FIX(R6): 4 segments/row (64 B/row, 16 KB total); previous version staged only 2.
    for (int i = 0; i < 4; ++i) {
        int c = i * 256 + tid;
        int rB = c >> 2, seg = c & 3;
        int g = rB >> 6, rem = rB & 63;              // rem = w2*16 + l
        int grow = g * 256 + (rem >> 4) * 64 + (rem & 15);
        uint4 v = *(const uint4*)(Wd + (size_t)grow * 256 + 64 + seg * 8);
        *(uint4*)(lds + 131072 + ((rB * 64 + seg * 16) ^ ((rB & 3) << 4))) = v;
    }
    // ---- register weight fragments ----
    bf16x8_t wr2[4][3];            // kt==2, jt in {1,2,3}
    #pragma unroll
    for (int g = 0; g < 4; ++g)
        #pragma unroll
        for (int jt = 1; jt < 4; ++jt)
            wr2[g][jt - 1] = *(const bf16x8_t*)(
                Wd + (size_t)(g * 256 + w * 64 + jt * 16 + lr) * 256 + 64 + kg8);
    bf16x8_t wr3[4][4][5];         // kt in [3,8)
    #pragma unroll
    for (int g = 0; g < 4; ++g)
        #pragma unroll
        for (int jt = 0; jt < 4; ++jt)
            #pragma unroll
            for (int kt = 3; kt < 8; ++kt)
                wr3[g][jt][kt - 3] = *(const bf16x8_t*)(
                    Wd + (size_t)(g * 256 + w * 64 + jt * 16 + lr) * 256 + kt * 32 + kg8);

    float cst[4][4];
    #pragma unroll
    for (int a = 0; a < 4; ++a)
        #pragma unroll
        for (int b = 0; b < 4; ++b) cst[a][b] = 0.f;

    __syncthreads();

    for (int tt = 0; tt < 512; ++tt) {
        const int t = d ? (511 - tt) : tt;

        // zx prefetch: (g, jt) -> 4 consecutive b (8B each)
        ushort4 zxv[4][4];
        #pragma unroll
        for (int g = 0; g < 4; ++g)
            #pragma unroll
            for (int jt = 0; jt < 4; ++jt)
                zxv[g][jt] = *(const ushort4*)(
                    Z + (size_t)t * 32768 + (g * 256 + w * 64 + jt * 16 + lr) * 32 + bh * 16 + kq * 4);

        f32x4_t acc[4][4];
        #pragma unroll
        for (int g = 0; g < 4; ++g)
            #pragma unroll
            for (int jt = 0; jt < 4; ++jt) acc[g][jt] = f32x4_t{0.f, 0.f, 0.f, 0.f};

        if (tt > 0) {
            #pragma unroll
            for (int kt = 0; kt < 8; ++kt) {
                bf16x8_t af = *(const bf16x8_t*)(
                    lds + hbase + ((lr * 512 + (kt * 32 + kg8) * 2) ^ ((lr & 7) << 4)));
                #pragma unroll
                for (int g = 0; g < 4; ++g)
                    #pragma unroll
                    for (int jt = 0; jt < 4; ++jt) {
                        bf16x8_t bf;
                        if (kt < 2) {
                            int row = g * 256 + w * 64 + jt * 16 + lr;
                            bf = *(const bf16x8_t*)(
                                lds + ((row * 128 + (kt * 32 + kg8) * 2) ^ ((row & 7) << 4)));
                        } else if (kt == 2 && jt == 0) {
                            int rB = g * 64 + w * 16 + lr;
                            bf = *(const bf16x8_t*)(
                                lds + 131072 + ((rB * 64 + kg8 * 2) ^ ((rB & 3) << 4)));
                        } else if (kt == 2) {
                            bf = wr2[g][jt - 1];
                        } else {
                            bf = wr3[g][jt][kt - 3];
                        }
                        acc[g][jt] = __builtin_amdgcn_mfma_f32_16x16x32_bf16(af, bf, acc[g][jt], 0, 0, 0);
                    }
            }
        }

        __syncthreads();   // all h reads complete (h region about to be overwritten)

        // gates fully in-register; write h -> LDS + Hb
        #pragma unroll
        for (int jt = 0; jt < 4; ++jt) {
            const int u = w * 64 + jt * 16 + lr;
            #pragma unroll
            for (int r = 0; r < 4; ++r) {
                float zi = acc[0][jt][r] + bf2f(((const unsigned short*)&zxv[0][jt])[r]);
                float zf = acc[1][jt][r] + bf2f(((const unsigned short*)&zxv[1][jt])[r]);
                float zg = acc[2][jt][r] + bf2f(((const unsigned short*)&zxv[2][jt])[r]);
                float zo = acc[3][jt][r] + bf2f(((const unsigned short*)&zxv[3][jt])[r]);
                float c = sigf(zf) * cst[jt][r] + sigf(zi) * tanhf_fast(zg);
                cst[jt][r] = c;
                float hh = sigf(zo) * tanhf_fast(c);
                unsigned short hb = f2bf(hh);
                int bl = kq * 4 + r;
                *(unsigned short*)(lds + hbase + ((bl * 512 + u * 2) ^ ((bl & 7) << 4))) = hb;
                Hb[((size_t)t * 32 + bh * 16 + bl) * 512 + d * 256 + u] = hb;
            }
        }
        __syncthreads();   // h writes visible for next step
    }
}

// ---------------- fused attention (bf16 in, bf16 out) ----------------
__global__ __launch_bounds__(256) void attn_fused(
    const unsigned short* __restrict__ qkv, unsigned short* __restrict__ outp)
{
    int s = blockIdx.x & 511;
    int h = blockIdx.x >> 9;
    __shared__ float qs[32][260];
    __shared__ float ks[32][260];
    __shared__ float vs[32][260];
    __shared__ float sc[32][36];
    int tid = threadIdx.x;
    for (int it = 0; it < 32; ++it) {
        const unsigned short* base = qkv + ((size_t)s * 32 + it) * 1536 + h * 256 + tid;
        qs[it][tid] = bf2f(base[0]);
        ks[it][tid] = bf2f(base[512]);
        vs[it][tid] = bf2f(base[1024]);
    }
    __syncthreads();
    int l = tid >> 3, m0 = (tid & 7) * 4;
    float a0 = 0, a1 = 0, a2 = 0, a3 = 0;
    for (int dd = 0; dd < 256; dd += 4) {
        float4 q4 = *(const float4*)&qs[l][dd];
        float4 k0v = *(const float4*)&ks[m0 + 0][dd];
        float4 k1v = *(const float4*)&ks[m0 + 1][dd];
        float4 k2v = *(const float4*)&ks[m0 + 2][dd];
        float4 k3v = *(const float4*)&ks[m0 + 3][dd];
        a0 += q4.x * k0v.x + q4.y * k0v.y + q4.z * k0v.z + q4.w * k0v.w;
        a1 += q4.x * k1v.x + q4.y * k1v.y + q4.z * k1v.z + q4.w * k1v.w;
        a2 += q4.x * k2v.x + q4.y * k2v.y + q4.z * k2v.z + q4.w * k2v.w;
        a3 += q4.x * k3v.x + q4.y * k3v.y + q4.z * k3v.z + q4.w * k3v.w;
    }
    sc[l][m0 + 0] = a0 * 0.0625f;
    sc[l][m0 + 1] = a1 * 0.0625f;
    sc[l][m0 + 2] = a2 * 0.0625f;
    sc[l][m0 + 3] = a3 * 0.0625f;
    __syncthreads();
    if (tid < 32) {
        float mx = -1e30f;
        for (int m = 0; m < 32; ++m) mx = fmaxf(mx, sc[tid][m]);
        float pr[32]; float sm = 0.f;
        for (int m = 0; m < 32; ++m) { pr[m] = __expf(sc[tid][m] - mx); sm += pr[m]; }
        float inv = 1.f / sm;
        for (int m = 0; m < 32; ++m) sc[tid][m] = pr[m] * inv;
    }
    __syncthreads();
    int l2 = tid >> 3, d0 = (tid & 7) * 32;
    float o[32] = {};
    for (int m = 0; m < 32; ++m) {
        float aw = sc[l2][m];
        #pragma unroll
        for (int dd = 0; dd < 32; dd += 4) {
            float4 v4 = *(const float4*)&vs[m][d0 + dd];
            o[dd] += aw * v4.x; o[dd + 1] += aw * v4.y; o[dd + 2] += aw * v4.z; o[dd + 3] += aw * v4.w;
        }
    }
    unsigned short* ob = outp + ((size_t)s * 32 + l2) * 512 + h * 256 + d0;
    #pragma unroll
    for (int dd = 0; dd < 32; dd += 4) {
        ushort4 pv;
        pv.x = f2bf(o[dd]); pv.y = f2bf(o[dd + 1]); pv.z = f2bf(o[dd + 2]); pv.w = f2bf(o[dd + 3]);
        *(ushort4*)(ob + dd) = pv;
    }
}

// ---------------- fc logits (A f32) ----------------
__global__ __launch_bounds__(256) void fc_logits(
    const float* __restrict__ A, const float* __restrict__ fcw, const float* __restrict__ fcb,
    float* __restrict__ outp)
{
    __shared__ float wsm[16][516];
    int tid = threadIdx.x;
    for (int idx = tid; idx < 8192; idx += 256) wsm[idx >> 9][idx & 511] = fcw[idx];
    __syncthreads();
    int r = blockIdx.x * 16 + (tid >> 4);
    int c = tid & 15;
    const float* ar = A + (size_t)r * 512;
    float acc = 0.f;
    for (int k = 0; k < 512; k += 4) {
        float4 a4 = *(const float4*)(ar + k);
        float4 w4 = *(const float4*)&wsm[c][k];
        acc += a4.x * w4.x + a4.y * w4.y + a4.z * w4.z + a4.w * w4.w;
    }
    int s = r >> 5, b = r & 31;
    outp[(size_t)b * 8192 + s * 16 + c] = acc + fcb[c];
}

// ---------------- CRF ----------------
__global__ __launch_bounds__(256) void crf_forward(
    const float* __restrict__ em, const int* __restrict__ labels,
    const float* __restrict__ cs, const float* __restrict__ ce, const float* __restrict__ ct,
    float* __restrict__ res)
{
    int b = blockIdx.x;
    int tid = threadIdx.x;
    int jj = tid >> 4, ii = tid & 15;
    __shared__ float trans[16][17];
    __shared__ float alpha[2][16];
    __shared__ float red[256];
    trans[tid >> 4][tid & 15] = ct[tid & 255];
    const float* emb_ = em + (size_t)b * 8192;
    const int* tg = labels + b * 512;
    float part = 0.f;
    for (int t = tid; t < 512; t += 256) {
        int cur = tg[t];
        part += emb_[t * 16 + cur] + (t == 0 ? cs[cur] : ct[tg[t - 1] * 16 + cur]);
    }
    red[tid] = part;
    if (tid < 16) alpha[0][tid] = cs[tid] + emb_[tid];
    __syncthreads();
    for (int off = 128; off > 0; off >>= 1) {
        if (tid < off) red[tid] += red[tid + off];
        __syncthreads();
    }
    for (int t = 1; t < 512; ++t) {
        int p = t & 1;
        float v = alpha[p ^ 1][ii] + trans[ii][jj];
        float mx = v;
        mx = fmaxf(mx, __shfl_xor(mx, 1));
        mx = fmaxf(mx, __shfl_xor(mx, 2));
        mx = fmaxf(mx, __shfl_xor(mx, 4));
        mx = fmaxf(mx, __shfl_xor(mx, 8));
        float e = __expf(v - mx);
        e += __shfl_xor(e, 1); e += __shfl_xor(e, 2); e += __shfl_xor(e, 4); e += __shfl_xor(e, 8);
        if (ii == 0) alpha[p][jj] = mx + __logf(e) + emb_[t * 16 + jj];
        __syncthreads();
    }
    if (tid == 0) {
        float mx = -1e30f;
        for (int c2 = 0; c2 < 16; ++c2) mx = fmaxf(mx, alpha[1][c2] + ce[c2]);
        float sm = 0.f;
        for (int c2 = 0; c2 < 16; ++c2) sm += __expf(alpha[1][c2] + ce[c2] - mx);
        float logZ = mx + __logf(sm);
        float score = red[0] + ce[tg[511]];
        res[b] = logZ - score;
    }
}

__global__ void crf_final(const float* __restrict__ res, float* __restrict__ nll)
{
    if (threadIdx.x == 0) {
        float s2 = 0.f;
        for (int b = 0; b < 32; ++b) s2 += res[b];
        nll[0] = s2;
    }
}

extern "C" void kernel_launch(void* const* d_in, const int* in_sizes, int n_in,
                              void* d_out, int out_size, void* d_ws, size_t ws_size,
                              hipStream_t stream)
{
    const int* x      = (const int*)d_in[0];
    const int* labels = (const int*)d_in[1];
    const float* emb  = (const float*)d_in[2];
    const float* wih  = (const float*)d_in[3];
    const float* whh  = (const float*)d_in[4];
    const float* bih  = (const float*)d_in[5];
    const float* bhh  = (const float*)d_in[6];
    const float* inw  = (const float*)d_in[7];
    const float* inb  = (const float*)d_in[8];
    const float* opw  = (const float*)d_in[9];
    const float* opb  = (const float*)d_in[10];
    const float* fcw  = (const float*)d_in[11];
    const float* fcb  = (const float*)d_in[12];
    const float* cs   = (const float*)d_in[13];
    const float* ce   = (const float*)d_in[14];
    const float* ct   = (const float*)d_in[15];
    float* out = (float*)d_out;

    // ws layout (MiB):
    //  [0,16)    Xb (embed out)       -> attnO (after qkv consumed)
    //  [16,48)   H0b [16,32)          -> OPout f32 [16,48); res at 16M (CRF)
    //  [32,48)   H1b
    //  [48,112)  Zfb [48,80), Zbb [80,112)   -> qkv [48,96)
    //  [112,120) wihb [112,116), whhb [116,118), inwb [118,119.5), opwb [119.5,120)
    char* ws = (char*)d_ws;
    const size_t MiB = 1ull << 20;
    unsigned short* Xb    = (unsigned short*)(ws);
    unsigned short* attnO = (unsigned short*)(ws);
    unsigned short* H0b   = (unsigned short*)(ws + 16 * MiB);
    float*          OPout = (float*)(ws + 16 * MiB);
    float*          res   = (float*)(ws + 16 * MiB);
    unsigned short* H1b   = (unsigned short*)(ws + 32 * MiB);
    unsigned short* Zfb   = (unsigned short*)(ws + 48 * MiB);
    unsigned short* qkv   = (unsigned short*)(ws + 48 * MiB);
    unsigned short* Zbb   = (unsigned short*)(ws + 80 * MiB);
    unsigned short* wihb  = (unsigned short*)(ws + 112 * MiB);
    unsigned short* whhb  = (unsigned short*)(ws + 116 * MiB);
    unsigned short* inwb  = (unsigned short*)(ws + 118 * MiB);
    unsigned short* opwb  = (unsigned short*)(ws + 119 * MiB + 512 * 1024);

    // 1) embedding gather + weight conversions
    embed_gather<<<16384, 128, 0, stream>>>(x, emb, Xb);
    conv_f2b<<<2048, 256, 0, stream>>>(wih, wihb, 2097152);
    conv_f2b<<<1024, 256, 0, stream>>>(whh, whhb, 1048576);
    conv_f2b<<<768, 256, 0, stream>>>(inw, inwb, 786432);
    conv_f2b<<<256, 256, 0, stream>>>(opw, opwb, 262144);

    // 2) two BiLSTM layers (Z stored permuted [t][n][32b]; recurrence sync-free)
    for (int l = 0; l < 2; ++l) {
        const unsigned short* Ain = l ? H0b : Xb;
        unsigned short* Ho        = l ? H1b : H0b;
        for (int dd = 0; dd < 2; ++dd) {
            gemm_bf16<2><<<dim3(256, 16), 256, 0, stream>>>(
                Ain, wihb + (size_t)(l * 2 + dd) * 524288,
                bih + (l * 2 + dd) * 1024, bhh + (l * 2 + dd) * 1024,
                dd ? (void*)Zbb : (void*)Zfb, 16384, 1024, 512);
        }
        lstm_rec4<<<4, 256, 0, stream>>>(Zfb, Zbb, whhb + (size_t)l * 524288, Ho);
    }

    // 3) MHA
    gemm_bf16<1><<<dim3(256, 24), 256, 0, stream>>>(H1b, inwb, inb, nullptr, (void*)qkv, 16384, 1536, 512);
    attn_fused<<<1024, 256, 0, stream>>>(qkv, attnO);
    gemm_bf16<0><<<dim3(256, 8), 256, 0, stream>>>(attnO, opwb, opb, nullptr, (void*)OPout, 16384, 512, 512);

    // 4) logits -> d_out
    fc_logits<<<1024, 256, 0, stream>>>(OPout, fcw, fcb, out);

    // 5) CRF
    crf_forward<<<32, 256, 0, stream>>>(out, labels, cs, ce, ct, res);
    crf_final<<<1, 64, 0, stream>>>(res, out + 262144);

    (void)in_sizes; (void)n_in; (void)out_size; (void)ws_size;
}

// Round 8
// 6176.139 us; speedup vs baseline: 1.6787x; 1.6787x over previous
//
#include <hip/hip_runtime.h>
#include <hip/hip_bf16.h>
#include <cstdint>

#define S_ 512
#define B_ 32
#define E_ 512
#define H_ 256
#define C_ 16

typedef float f32x4_t __attribute__((ext_vector_type(4)));
typedef __bf16 bf16x8_t __attribute__((ext_vector_type(8)));

__device__ __forceinline__ float bf2f(unsigned short u) {
    return __uint_as_float(((unsigned int)u) << 16);
}
__device__ __forceinline__ unsigned short f2bf(float f) {
    unsigned int u = __float_as_uint(f);
    unsigned int r = (u + 0x7FFFu + ((u >> 16) & 1u)) >> 16;
    return (unsigned short)r;
}
__device__ __forceinline__ float sigf(float x) { return 1.f / (1.f + __expf(-x)); }
__device__ __forceinline__ float tanhf_fast(float x) {
    float e = __expf(-2.f * fabsf(x));
    float r = (1.f - e) / (1.f + e);
    return x >= 0.f ? r : -r;
}

// ---------------- embedding gather -> bf16 X[s*32+b][0:512] ----------------
__global__ __launch_bounds__(128) void embed_gather(
    const int* __restrict__ x, const float* __restrict__ emb, unsigned short* __restrict__ X)
{
    int row = blockIdx.x;           // s*32 + b
    int s = row >> 5, b = row & 31;
    int idx = x[b * S_ + s];
    float4 v = ((const float4*)(emb + (size_t)idx * E_))[threadIdx.x];
    ushort4 o; o.x = f2bf(v.x); o.y = f2bf(v.y); o.z = f2bf(v.z); o.w = f2bf(v.w);
    ((ushort4*)(X + (size_t)row * E_))[threadIdx.x] = o;
}

// ---------------- f32 -> bf16 converter (n multiple of 4) ----------------
__global__ __launch_bounds__(256) void conv_f2b(
    const float* __restrict__ src, unsigned short* __restrict__ dst, int n)
{
    int i = (blockIdx.x * 256 + threadIdx.x) * 4;
    if (i < n) {
        float4 v = *(const float4*)(src + i);
        ushort4 o; o.x = f2bf(v.x); o.y = f2bf(v.y); o.z = f2bf(v.z); o.w = f2bf(v.w);
        *(ushort4*)(dst + i) = o;
    }
}

// ---------------- bf16 MFMA GEMM: C[M,N] = A[M,K] @ W[N,K]^T (+b1+b2) ----------------
// 64x64 tile, 256 thr (4 waves), BK=64.
// STORE_MODE: 0 = f32 row-major, 1 = bf16 row-major, 2 = bf16 permuted [m>>5][n][32 b]
template<int STORE_MODE>
__global__ __launch_bounds__(256) void gemm_bf16(
    const unsigned short* __restrict__ A, const unsigned short* __restrict__ W,
    const float* __restrict__ b1, const float* __restrict__ b2,
    void* __restrict__ Cout, int M, int N, int K)
{
    __shared__ __align__(16) char lds[16384];   // A-tile 8K + W-tile 8K, swizzled
    char* asb = lds;
    char* wsb = lds + 8192;
    const int tid = threadIdx.x;
    const int m0 = blockIdx.x * 64, n0 = blockIdx.y * 64;
    const int w = tid >> 6, L = tid & 63;
    const int sr = tid >> 2, sq = tid & 3;
    const int mrow = L & 15, kg = (L >> 4) * 8;
    f32x4_t acc[4];
    #pragma unroll
    for (int ni = 0; ni < 4; ++ni) acc[ni] = f32x4_t{0.f, 0.f, 0.f, 0.f};

    for (int k0 = 0; k0 < K; k0 += 64) {
        uint4 av1 = *(const uint4*)(A + (size_t)(m0 + sr) * K + k0 + sq * 16);
        uint4 av2 = *(const uint4*)(A + (size_t)(m0 + sr) * K + k0 + sq * 16 + 8);
        uint4 wv1 = *(const uint4*)(W + (size_t)(n0 + sr) * K + k0 + sq * 16);
        uint4 wv2 = *(const uint4*)(W + (size_t)(n0 + sr) * K + k0 + sq * 16 + 8);
        __syncthreads();
        int sw = (sr & 7) << 4;
        *(uint4*)(asb + ((sr * 128 + sq * 32) ^ sw))      = av1;
        *(uint4*)(asb + ((sr * 128 + sq * 32 + 16) ^ sw)) = av2;
        *(uint4*)(wsb + ((sr * 128 + sq * 32) ^ sw))      = wv1;
        *(uint4*)(wsb + ((sr * 128 + sq * 32 + 16) ^ sw)) = wv2;
        __syncthreads();
        #pragma unroll
        for (int kb = 0; kb < 2; ++kb) {
            int kl = kb * 32 + kg;
            int ar = w * 16 + mrow;
            bf16x8_t a = *(const bf16x8_t*)(asb + ((ar * 128 + kl * 2) ^ ((ar & 7) << 4)));
            #pragma unroll
            for (int ni = 0; ni < 4; ++ni) {
                int nr = ni * 16 + mrow;
                bf16x8_t b = *(const bf16x8_t*)(wsb + ((nr * 128 + kl * 2) ^ ((nr & 7) << 4)));
                acc[ni] = __builtin_amdgcn_mfma_f32_16x16x32_bf16(a, b, acc[ni], 0, 0, 0);
            }
        }
    }
    #pragma unroll
    for (int ni = 0; ni < 4; ++ni) {
        int n = n0 + ni * 16 + mrow;
        float bb = (b1 ? b1[n] : 0.f) + (b2 ? b2[n] : 0.f);
        #pragma unroll
        for (int r = 0; r < 4; ++r) {
            int m = m0 + w * 16 + (L >> 4) * 4 + r;
            float v = acc[ni][r] + bb;
            if (STORE_MODE == 2) {
                int tq = m >> 5, b = m & 31;
                ((unsigned short*)Cout)[((size_t)tq * N + n) * 32 + b] = f2bf(v);
            } else if (STORE_MODE == 1) {
                ((unsigned short*)Cout)[(size_t)m * N + n] = f2bf(v);
            } else {
                ((float*)Cout)[(size_t)m * N + n] = v;
            }
        }
    }
}

// ---------------- LSTM recurrence v5: 4 blocks = 2 dir x 2 batch-halves, 512 thr ----------
// Sync-free (no cross-block exchange). 8 waves (2/SIMD, 256 VGPR cap). Wave w owns
// 32 units x 4 gates. LDS 160KB: kt{0,1} all rows (128K) + kt2/jt0/g<3 (24K) + h (8K).
// Registers: kt[3,8) (160) + 5 kt2 leftovers (20) + acc 32 (init'd from Zx) + cst 8.
__global__ __launch_bounds__(512, 2) void lstm_rec5(
    const unsigned short* __restrict__ Zf,   // [512][1024][32] bf16 permuted
    const unsigned short* __restrict__ Zb,
    const unsigned short* __restrict__ whhb, // [2][1024][256] bf16 (this layer)
    unsigned short* __restrict__ Hb)         // [512*32][512] bf16
{
    __shared__ __align__(16) char lds[163840];  // A:0..128K, B:128K..152K, h:152K..160K
    const int tid = threadIdx.x;
    const int d  = blockIdx.x >> 1;
    const int bh = blockIdx.x & 1;
    const int w = tid >> 6, L = tid & 63;
    const int lr = L & 15;
    const int kq = L >> 4;
    const int kg8 = kq * 8;
    const unsigned short* Z = d ? Zb : Zf;
    const unsigned short* Wd = whhb + (size_t)d * 262144;
    const int hbase = 155648;

    // ---- stage LDS region A: all 1024 rows, k in [0,64): 8192 chunks of 16B ----
    for (int i = 0; i < 16; ++i) {
        int c = i * 512 + tid;
        int row = c >> 3, seg = c & 7;
        uint4 v = *(const uint4*)(Wd + (size_t)row * 256 + seg * 8);
        *(uint4*)(lds + ((row * 128 + seg * 16) ^ ((row & 7) << 4))) = v;
    }
    // ---- stage LDS region B: kt2 (k in [64,96)), jt==0, g in {0,1,2}: 384 rows ----
    for (int i = 0; i < 3; ++i) {
        int c = i * 512 + tid;
        int rB = c >> 2, seg = c & 3;
        int g = rB >> 7, rem = rB & 127;
        int grow = g * 256 + (rem >> 4) * 32 + (rem & 15);   // jt=0
        uint4 v = *(const uint4*)(Wd + (size_t)grow * 256 + 64 + seg * 8);
        *(uint4*)(lds + 131072 + ((rB * 64 + seg * 16) ^ ((rB & 3) << 4))) = v;
    }
    // ---- register weight fragments ----
    bf16x8_t wr[5][4][2];      // kt in [3,8) x gate x jt
    #pragma unroll
    for (int kk = 0; kk < 5; ++kk)
        #pragma unroll
        for (int g = 0; g < 4; ++g)
            #pragma unroll
            for (int jt = 0; jt < 2; ++jt)
                wr[kk][g][jt] = *(const bf16x8_t*)(
                    Wd + (size_t)(g * 256 + w * 32 + jt * 16 + lr) * 256 + (kk + 3) * 32 + kg8);
    bf16x8_t wk2_j1[4];        // kt2, jt1, all gates
    #pragma unroll
    for (int g = 0; g < 4; ++g)
        wk2_j1[g] = *(const bf16x8_t*)(
            Wd + (size_t)(g * 256 + w * 32 + 16 + lr) * 256 + 64 + kg8);
    bf16x8_t wk2_j0g3 = *(const bf16x8_t*)(
        Wd + (size_t)(3 * 256 + w * 32 + lr) * 256 + 64 + kg8);

    float cst[2][4] = {{0.f, 0.f, 0.f, 0.f}, {0.f, 0.f, 0.f, 0.f}};
    __syncthreads();

    for (int tt = 0; tt < 512; ++tt) {
        const int t = d ? (511 - tt) : tt;

        // acc init directly from Zx (bf16 -> f32): acc[g][jt][r] = zx[batch kq*4+r][row]
        f32x4_t acc[4][2];
        #pragma unroll
        for (int g = 0; g < 4; ++g)
            #pragma unroll
            for (int jt = 0; jt < 2; ++jt) {
                ushort4 z = *(const ushort4*)(
                    Z + (size_t)t * 32768 + (g * 256 + w * 32 + jt * 16 + lr) * 32 + bh * 16 + kq * 4);
                acc[g][jt] = f32x4_t{bf2f(z.x), bf2f(z.y), bf2f(z.z), bf2f(z.w)};
            }

        if (tt > 0) {
            #pragma unroll
            for (int kt = 0; kt < 8; ++kt) {
                bf16x8_t af = *(const bf16x8_t*)(
                    lds + hbase + ((lr * 512 + (kt * 32 + kg8) * 2) ^ ((lr & 7) << 4)));
                #pragma unroll
                for (int g = 0; g < 4; ++g)
                    #pragma unroll
                    for (int jt = 0; jt < 2; ++jt) {
                        bf16x8_t bf;
                        if (kt < 2) {
                            int row = g * 256 + w * 32 + jt * 16 + lr;
                            bf = *(const bf16x8_t*)(
                                lds + ((row * 128 + (kt * 32 + kg8) * 2) ^ ((row & 7) << 4)));
                        } else if (kt == 2) {
                            if (jt == 0 && g < 3) {
                                int rB = g * 128 + w * 16 + lr;
                                bf = *(const bf16x8_t*)(
                                    lds + 131072 + ((rB * 64 + kg8 * 2) ^ ((rB & 3) << 4)));
                            } else if (jt == 0) {
                                bf = wk2_j0g3;
                            } else {
                                bf = wk2_j1[g];
                            }
                        } else {
                            bf = wr[kt - 3][g][jt];
                        }
                        acc[g][jt] = __builtin_amdgcn_mfma_f32_16x16x32_bf16(af, bf, acc[g][jt], 0, 0, 0);
                    }
            }
        }

        __syncthreads();   // h reads complete (region about to be overwritten)

        // gates in-register (acc already includes zx); write h -> LDS + Hb
        #pragma unroll
        for (int jt = 0; jt < 2; ++jt) {
            const int u = w * 32 + jt * 16 + lr;
            #pragma unroll
            for (int r = 0; r < 4; ++r) {
                float iv = sigf(acc[0][jt][r]);
                float fv = sigf(acc[1][jt][r]);
                float gv = tanhf_fast(acc[2][jt][r]);
                float ov = sigf(acc[3][jt][r]);
                float c = fv * cst[jt][r] + iv * gv;
                cst[jt][r] = c;
                float hh = ov * tanhf_fast(c);
                unsigned short hb = f2bf(hh);
                int bl = kq * 4 + r;
                *(unsigned short*)(lds + hbase + ((bl * 512 + u * 2) ^ ((bl & 7) << 4))) = hb;
                Hb[((size_t)t * 32 + bh * 16 + bl) * 512 + d * 256 + u] = hb;
            }
        }
        __syncthreads();   // h writes visible for next step
    }
}

// ---------------- fused attention (bf16 in, bf16 out) ----------------
__global__ __launch_bounds__(256) void attn_fused(
    const unsigned short* __restrict__ qkv, unsigned short* __restrict__ outp)
{
    int s = blockIdx.x & 511;
    int h = blockIdx.x >> 9;
    __shared__ float qs[32][260];
    __shared__ float ks[32][260];
    __shared__ float vs[32][260];
    __shared__ float sc[32][36];
    int tid = threadIdx.x;
    for (int it = 0; it < 32; ++it) {
        const unsigned short* base = qkv + ((size_t)s * 32 + it) * 1536 + h * 256 + tid;
        qs[it][tid] = bf2f(base[0]);
        ks[it][tid] = bf2f(base[512]);
        vs[it][tid] = bf2f(base[1024]);
    }
    __syncthreads();
    int l = tid >> 3, m0 = (tid & 7) * 4;
    float a0 = 0, a1 = 0, a2 = 0, a3 = 0;
    for (int dd = 0; dd < 256; dd += 4) {
        float4 q4 = *(const float4*)&qs[l][dd];
        float4 k0v = *(const float4*)&ks[m0 + 0][dd];
        float4 k1v = *(const float4*)&ks[m0 + 1][dd];
        float4 k2v = *(const float4*)&ks[m0 + 2][dd];
        float4 k3v = *(const float4*)&ks[m0 + 3][dd];
        a0 += q4.x * k0v.x + q4.y * k0v.y + q4.z * k0v.z + q4.w * k0v.w;
        a1 += q4.x * k1v.x + q4.y * k1v.y + q4.z * k1v.z + q4.w * k1v.w;
        a2 += q4.x * k2v.x + q4.y * k2v.y + q4.z * k2v.z + q4.w * k2v.w;
        a3 += q4.x * k3v.x + q4.y * k3v.y + q4.z * k3v.z + q4.w * k3v.w;
    }
    sc[l][m0 + 0] = a0 * 0.0625f;
    sc[l][m0 + 1] = a1 * 0.0625f;
    sc[l][m0 + 2] = a2 * 0.0625f;
    sc[l][m0 + 3] = a3 * 0.0625f;
    __syncthreads();
    if (tid < 32) {
        float mx = -1e30f;
        for (int m = 0; m < 32; ++m) mx = fmaxf(mx, sc[tid][m]);
        float pr[32]; float sm = 0.f;
        for (int m = 0; m < 32; ++m) { pr[m] = __expf(sc[tid][m] - mx); sm += pr[m]; }
        float inv = 1.f / sm;
        for (int m = 0; m < 32; ++m) sc[tid][m] = pr[m] * inv;
    }
    __syncthreads();
    int l2 = tid >> 3, d0 = (tid & 7) * 32;
    float o[32] = {};
    for (int m = 0; m < 32; ++m) {
        float aw = sc[l2][m];
        #pragma unroll
        for (int dd = 0; dd < 32; dd += 4) {
            float4 v4 = *(const float4*)&vs[m][d0 + dd];
            o[dd] += aw * v4.x; o[dd + 1] += aw * v4.y; o[dd + 2] += aw * v4.z; o[dd + 3] += aw * v4.w;
        }
    }
    unsigned short* ob = outp + ((size_t)s * 32 + l2) * 512 + h * 256 + d0;
    #pragma unroll
    for (int dd = 0; dd < 32; dd += 4) {
        ushort4 pv;
        pv.x = f2bf(o[dd]); pv.y = f2bf(o[dd + 1]); pv.z = f2bf(o[dd + 2]); pv.w = f2bf(o[dd + 3]);
        *(ushort4*)(ob + dd) = pv;
    }
}

// ---------------- fc logits (A f32) ----------------
__global__ __launch_bounds__(256) void fc_logits(
    const float* __restrict__ A, const float* __restrict__ fcw, const float* __restrict__ fcb,
    float* __restrict__ outp)
{
    __shared__ float wsm[16][516];
    int tid = threadIdx.x;
    for (int idx = tid; idx < 8192; idx += 256) wsm[idx >> 9][idx & 511] = fcw[idx];
    __syncthreads();
    int r = blockIdx.x * 16 + (tid >> 4);
    int c = tid & 15;
    const float* ar = A + (size_t)r * 512;
    float acc = 0.f;
    for (int k = 0; k < 512; k += 4) {
        float4 a4 = *(const float4*)(ar + k);
        float4 w4 = *(const float4*)&wsm[c][k];
        acc += a4.x * w4.x + a4.y * w4.y + a4.z * w4.z + a4.w * w4.w;
    }
    int s = r >> 5, b = r & 31;
    outp[(size_t)b * 8192 + s * 16 + c] = acc + fcb[c];
}

// ---------------- CRF ----------------
__global__ __launch_bounds__(256) void crf_forward(
    const float* __restrict__ em, const int* __restrict__ labels,
    const float* __restrict__ cs, const float* __restrict__ ce, const float* __restrict__ ct,
    float* __restrict__ res)
{
    int b = blockIdx.x;
    int tid = threadIdx.x;
    int jj = tid >> 4, ii = tid & 15;
    __shared__ float trans[16][17];
    __shared__ float alpha[2][16];
    __shared__ float red[256];
    trans[tid >> 4][tid & 15] = ct[tid & 255];
    const float* emb_ = em + (size_t)b * 8192;
    const int* tg = labels + b * 512;
    float part = 0.f;
    for (int t = tid; t < 512; t += 256) {
        int cur = tg[t];
        part += emb_[t * 16 + cur] + (t == 0 ? cs[cur] : ct[tg[t - 1] * 16 + cur]);
    }
    red[tid] = part;
    if (tid < 16) alpha[0][tid] = cs[tid] + emb_[tid];
    __syncthreads();
    for (int off = 128; off > 0; off >>= 1) {
        if (tid < off) red[tid] += red[tid + off];
        __syncthreads();
    }
    for (int t = 1; t < 512; ++t) {
        int p = t & 1;
        float v = alpha[p ^ 1][ii] + trans[ii][jj];
        float mx = v;
        mx = fmaxf(mx, __shfl_xor(mx, 1));
        mx = fmaxf(mx, __shfl_xor(mx, 2));
        mx = fmaxf(mx, __shfl_xor(mx, 4));
        mx = fmaxf(mx, __shfl_xor(mx, 8));
        float e = __expf(v - mx);
        e += __shfl_xor(e, 1); e += __shfl_xor(e, 2); e += __shfl_xor(e, 4); e += __shfl_xor(e, 8);
        if (ii == 0) alpha[p][jj] = mx + __logf(e) + emb_[t * 16 + jj];
        __syncthreads();
    }
    if (tid == 0) {
        float mx = -1e30f;
        for (int c2 = 0; c2 < 16; ++c2) mx = fmaxf(mx, alpha[1][c2] + ce[c2]);
        float sm = 0.f;
        for (int c2 = 0; c2 < 16; ++c2) sm += __expf(alpha[1][c2] + ce[c2] - mx);
        float logZ = mx + __logf(sm);
        float score = red[0] + ce[tg[511]];
        res[b] = logZ - score;
    }
}

__global__ void crf_final(const float* __restrict__ res, float* __restrict__ nll)
{
    if (threadIdx.x == 0) {
        float s2 = 0.f;
        for (int b = 0; b < 32; ++b) s2 += res[b];
        nll[0] = s2;
    }
}

extern "C" void kernel_launch(void* const* d_in, const int* in_sizes, int n_in,
                              void* d_out, int out_size, void* d_ws, size_t ws_size,
                              hipStream_t stream)
{
    const int* x      = (const int*)d_in[0];
    const int* labels = (const int*)d_in[1];
    const float* emb  = (const float*)d_in[2];
    const float* wih  = (const float*)d_in[3];
    const float* whh  = (const float*)d_in[4];
    const float* bih  = (const float*)d_in[5];
    const float* bhh  = (const float*)d_in[6];
    const float* inw  = (const float*)d_in[7];
    const float* inb  = (const float*)d_in[8];
    const float* opw  = (const float*)d_in[9];
    const float* opb  = (const float*)d_in[10];
    const float* fcw  = (const float*)d_in[11];
    const float* fcb  = (const float*)d_in[12];
    const float* cs   = (const float*)d_in[13];
    const float* ce   = (const float*)d_in[14];
    const float* ct   = (const float*)d_in[15];
    float* out = (float*)d_out;

    // ws layout (MiB):
    //  [0,16)    Xb (embed out)       -> attnO (after qkv consumed)
    //  [16,48)   H0b [16,32)          -> OPout f32 [16,48); res at 16M (CRF)
    //  [32,48)   H1b
    //  [48,112)  Zfb [48,80), Zbb [80,112)   -> qkv [48,96)
    //  [112,120) wihb [112,116), whhb [116,118), inwb [118,119.5), opwb [119.5,120)
    char* ws = (char*)d_ws;
    const size_t MiB = 1ull << 20;
    unsigned short* Xb    = (unsigned short*)(ws);
    unsigned short* attnO = (unsigned short*)(ws);
    unsigned short* H0b   = (unsigned short*)(ws + 16 * MiB);
    float*          OPout = (float*)(ws + 16 * MiB);
    float*          res   = (float*)(ws + 16 * MiB);
    unsigned short* H1b   = (unsigned short*)(ws + 32 * MiB);
    unsigned short* Zfb   = (unsigned short*)(ws + 48 * MiB);
    unsigned short* qkv   = (unsigned short*)(ws + 48 * MiB);
    unsigned short* Zbb   = (unsigned short*)(ws + 80 * MiB);
    unsigned short* wihb  = (unsigned short*)(ws + 112 * MiB);
    unsigned short* whhb  = (unsigned short*)(ws + 116 * MiB);
    unsigned short* inwb  = (unsigned short*)(ws + 118 * MiB);
    unsigned short* opwb  = (unsigned short*)(ws + 119 * MiB + 512 * 1024);

    // 1) embedding gather + weight conversions
    embed_gather<<<16384, 128, 0, stream>>>(x, emb, Xb);
    conv_f2b<<<2048, 256, 0, stream>>>(wih, wihb, 2097152);
    conv_f2b<<<1024, 256, 0, stream>>>(whh, whhb, 1048576);
    conv_f2b<<<768, 256, 0, stream>>>(inw, inwb, 786432);
    conv_f2b<<<256, 256, 0, stream>>>(opw, opwb, 262144);

    // 2) two BiLSTM layers (Z stored permuted [t][n][32b]; recurrence sync-free)
    for (int l = 0; l < 2; ++l) {
        const unsigned short* Ain = l ? H0b : Xb;
        unsigned short* Ho        = l ? H1b : H0b;
        for (int dd = 0; dd < 2; ++dd) {
            gemm_bf16<2><<<dim3(256, 16), 256, 0, stream>>>(
                Ain, wihb + (size_t)(l * 2 + dd) * 524288,
                bih + (l * 2 + dd) * 1024, bhh + (l * 2 + dd) * 1024,
                dd ? (void*)Zbb : (void*)Zfb, 16384, 1024, 512);
        }
        lstm_rec5<<<4, 512, 0, stream>>>(Zfb, Zbb, whhb + (size_t)l * 524288, Ho);
    }

    // 3) MHA
    gemm_bf16<1><<<dim3(256, 24), 256, 0, stream>>>(H1b, inwb, inb, nullptr, (void*)qkv, 16384, 1536, 512);
    attn_fused<<<1024, 256, 0, stream>>>(qkv, attnO);
    gemm_bf16<0><<<dim3(256, 8), 256, 0, stream>>>(attnO, opwb, opb, nullptr, (void*)OPout, 16384, 512, 512);

    // 4) logits -> d_out
    fc_logits<<<1024, 256, 0, stream>>>(OPout, fcw, fcb, out);

    // 5) CRF
    crf_forward<<<32, 256, 0, stream>>>(out, labels, cs, ce, ct, res);
    crf_final<<<1, 64, 0, stream>>>(res, out + 262144);

    (void)in_sizes; (void)n_in; (void)out_size; (void)ws_size;
}